// Round 2
// baseline (151.670 us; speedup 1.0000x reference)
//
#include <hip/hip_runtime.h>
#include <stdint.h>

#define Hs 96
#define Ws 96
#define HW 9216
#define TILE 96
#define NT 384
#define WROW 296      // padded weight row in halfs (288 + 8)
#define WROWB 592     // bytes

typedef _Float16 h2 __attribute__((ext_vector_type(2)));
typedef _Float16 f16x8 __attribute__((ext_vector_type(8)));
typedef float f32x4 __attribute__((ext_vector_type(4)));

// ---------------- kernel 1: NCHW fp32 -> NHWC fp16 ----------------
__global__ __launch_bounds__(256) void k_transpose(const float* __restrict__ in,
                                                   _Float16* __restrict__ cl) {
  __shared__ _Float16 lt[32 * 68];
  int tid = threadIdx.x;
  int blk = blockIdx.x;
  int xt = blk % 3;
  int r = blk / 3;
  int y = r % Hs;
  int b = r / Hs;
  int x0 = xt * 32;
  {
    int xx = tid & 31, cc = tid >> 5;
    const float* src = in + (size_t)b * 64 * HW + y * Ws + x0 + xx;
#pragma unroll
    for (int i = 0; i < 8; ++i) {
      int c = cc * 8 + i;
      lt[xx * 68 + c] = (_Float16)src[(size_t)c * HW];
    }
  }
  __syncthreads();
  {
    int c4 = tid & 15, pg = tid >> 4;
    _Float16* dst = cl + ((size_t)(b * Hs + y) * Ws + x0) * 64 + c4 * 4;
#pragma unroll
    for (int i = 0; i < 2; ++i) {
      int x = pg * 2 + i;
      *(uint2*)(dst + (size_t)x * 64) = *(const uint2*)(lt + x * 68 + c4 * 4);
    }
  }
}

// ------- kernel 2: weight fp32 [O][C][9] -> fp16 [ck][O][tap*32+c'] -------
__global__ __launch_bounds__(576) void k_wconv(const float* __restrict__ w,
                                               _Float16* __restrict__ wbf) {
  int o = blockIdx.x;    // 64
  int r = threadIdx.x;   // 576
  int tap = r >> 6, c = r & 63;
  int ck = c >> 5, cc = c & 31;
  wbf[((ck * 64 + o) * 288) + tap * 32 + cc] = (_Float16)w[(o * 64 + c) * 9 + tap];
}

// ---------------- kernel 3: fused sampling + split-K implicit GEMM --------
__global__ __launch_bounds__(384, 4) void k_main(
    const _Float16* __restrict__ incl, const float* __restrict__ off,
    const float* __restrict__ msk, const _Float16* __restrict__ wbf,
    const float* __restrict__ bias, float* __restrict__ out) {
  __shared__ _Float16 wlds[64 * WROW];   // 37,888 B
  __shared__ uint4 preU[9 * TILE];       // 13,824 B   {addr|dx|dy<<1, w00|w01, w10|w11, -}

  int tid = threadIdx.x;
  int blk = blockIdx.x;
  int ck = (blk >= 768) ? 1 : 0;
  int rb0 = blk - (ck ? 768 : 0);
  int b = rb0 & 7;                 // XCD swizzle; ck-partner is blk+768 (same residue)
  int q0 = (rb0 >> 3) * TILE;      // pixel tile base (96 tiles/image)

  // phase 0: this ck-half's weights -> LDS, rows padded to 296 halfs
  {
    const char* src = (const char*)wbf + ck * 36864;
    char* dst = (char*)wlds;
#pragma unroll
    for (int i = tid; i < 2304; i += NT) {
      int row = i / 36, s = i - row * 36;
      *(uint4*)(dst + row * WROWB + s * 16) = *(const uint4*)(src + row * 576 + s * 16);
    }
  }

  // phase 1: per-(pixel,tap) packed corner address + bilinear weights
  for (int i = tid; i < 9 * TILE; i += NT) {
    int t = i / TILE, p = i - t * TILE;
    int q = q0 + p;
    int qy = q / 96, qx = q - qy * 96;
    int ty = t / 3, tx = t - ty * 3;
    float dy = off[(size_t)(b * 18 + 2 * t) * HW + q];
    float dx = off[(size_t)(b * 18 + 2 * t + 1) * HW + q];
    float mv = msk[(size_t)(b * 9 + t) * HW + q];
    float yf = (float)(qy - 1 + ty) + dy;
    float xf = (float)(qx - 1 + tx) + dx;
    float y0f = floorf(yf), x0f = floorf(xf);
    float wy = yf - y0f, wx = xf - x0f;
    int y0 = (int)y0f, x0i = (int)x0f;
    int y1 = y0 + 1, x1 = x0i + 1;
    bool yv0 = (y0 >= 0) && (y0 < Hs);
    bool yv1 = (y1 >= 0) && (y1 < Hs);
    bool xv0 = (x0i >= 0) && (x0i < Ws);
    bool xv1 = (x1 >= 0) && (x1 < Ws);
    int y0c = min(max(y0, 0), Hs - 1), y1c = min(max(y1, 0), Hs - 1);
    int x0c = min(max(x0i, 0), Ws - 1), x1c = min(max(x1, 0), Ws - 1);
    unsigned a00 = (unsigned)(b * HW + y0c * 96 + x0c) * 128u;
    unsigned fdx = (unsigned)(x1c - x0c);        // 0/1
    unsigned fdy = (unsigned)(y1c - y0c);        // 0/1
    float omy = 1.f - wy, omx = 1.f - wx;
    float f00 = omy * omx * mv * ((yv0 && xv0) ? 1.f : 0.f);
    float f01 = omy * wx  * mv * ((yv0 && xv1) ? 1.f : 0.f);
    float f10 = wy  * omx * mv * ((yv1 && xv0) ? 1.f : 0.f);
    float f11 = wy  * wx  * mv * ((yv1 && xv1) ? 1.f : 0.f);
    uint4 u;
    u.x = a00 | fdx | (fdy << 1);
    u.y = __builtin_bit_cast(unsigned, __builtin_amdgcn_cvt_pkrtz(f00, f01));
    u.z = __builtin_bit_cast(unsigned, __builtin_amdgcn_cvt_pkrtz(f10, f11));
    u.w = 0;
    preU[i] = u;
  }
  __syncthreads();

  // phase 2: gather + packed-fp16 bilinear + MFMA (K=32 per tap)
  int lane = tid & 63;
  int wid = tid >> 6;          // 0..5
  int n = lane & 15;
  int quad16 = (lane >> 4) * 16;
  int p = wid * 16 + n;
  int ckoff = ck * 64 + quad16;
  const char* inb = (const char*)incl;
  const char* wb = (const char*)wlds + n * WROWB + quad16;

  f32x4 acc[4];
#pragma unroll
  for (int mt = 0; mt < 4; ++mt) {
    f32x4 z = {0.f, 0.f, 0.f, 0.f};
    acc[mt] = z;
  }

  for (int tap = 0; tap < 9; ++tap) {
    uint4 u = preU[tap * TILE + p];
    unsigned ax = u.x;
    int a00 = (int)(ax & ~127u) + ckoff;
    int a01 = a00 + ((ax & 1) << 7);
    int a10 = a00 + ((ax & 2) * 6144);
    int a11 = a10 + ((ax & 1) << 7);
    h2 w00 = __builtin_bit_cast(h2, __builtin_amdgcn_perm(u.y, u.y, 0x01000100u));
    h2 w01 = __builtin_bit_cast(h2, __builtin_amdgcn_perm(u.y, u.y, 0x03020302u));
    h2 w10 = __builtin_bit_cast(h2, __builtin_amdgcn_perm(u.z, u.z, 0x01000100u));
    h2 w11 = __builtin_bit_cast(h2, __builtin_amdgcn_perm(u.z, u.z, 0x03020302u));
    uint4 g00 = *(const uint4*)(inb + a00);
    uint4 g01 = *(const uint4*)(inb + a01);
    uint4 g10 = *(const uint4*)(inb + a10);
    uint4 g11 = *(const uint4*)(inb + a11);
    union { unsigned u[4]; f16x8 v; } bf;
    bf.u[0] = __builtin_bit_cast(unsigned,
        (h2)(w00 * __builtin_bit_cast(h2, g00.x) + w01 * __builtin_bit_cast(h2, g01.x) +
             w10 * __builtin_bit_cast(h2, g10.x) + w11 * __builtin_bit_cast(h2, g11.x)));
    bf.u[1] = __builtin_bit_cast(unsigned,
        (h2)(w00 * __builtin_bit_cast(h2, g00.y) + w01 * __builtin_bit_cast(h2, g01.y) +
             w10 * __builtin_bit_cast(h2, g10.y) + w11 * __builtin_bit_cast(h2, g11.y)));
    bf.u[2] = __builtin_bit_cast(unsigned,
        (h2)(w00 * __builtin_bit_cast(h2, g00.z) + w01 * __builtin_bit_cast(h2, g01.z) +
             w10 * __builtin_bit_cast(h2, g10.z) + w11 * __builtin_bit_cast(h2, g11.z)));
    bf.u[3] = __builtin_bit_cast(unsigned,
        (h2)(w00 * __builtin_bit_cast(h2, g00.w) + w01 * __builtin_bit_cast(h2, g01.w) +
             w10 * __builtin_bit_cast(h2, g10.w) + w11 * __builtin_bit_cast(h2, g11.w)));
    const char* wrow = wb + tap * 64;
#pragma unroll
    for (int mt = 0; mt < 4; ++mt) {
      f16x8 af = *(const f16x8*)(wrow + mt * (16 * WROWB));
      acc[mt] = __builtin_amdgcn_mfma_f32_16x16x32_f16(af, bf.v, acc[mt], 0, 0, 0);
    }
  }

  // epilogue: atomic accumulate the two K-halves; ck=0 carries the bias
  int pix = q0 + p;
  float* op = out + (size_t)b * 64 * HW + pix;
  int mrow = quad16 >> 2;
#pragma unroll
  for (int mt = 0; mt < 4; ++mt) {
#pragma unroll
    for (int r = 0; r < 4; ++r) {
      int m = mt * 16 + mrow + r;
      float v = acc[mt][r];
      if (ck == 0) v += bias[m];
      unsafeAtomicAdd(op + (size_t)m * HW, v);
    }
  }
}

extern "C" void kernel_launch(void* const* d_in, const int* in_sizes, int n_in,
                              void* d_out, int out_size, void* d_ws, size_t ws_size,
                              hipStream_t stream) {
  const float* input = (const float*)d_in[0];
  const float* offset = (const float*)d_in[1];
  const float* mask = (const float*)d_in[2];
  const float* weight = (const float*)d_in[3];
  const float* bias = (const float*)d_in[4];
  float* out = (float*)d_out;

  _Float16* incl = (_Float16*)d_ws;                            // 9,437,184 B
  _Float16* wbf = (_Float16*)((char*)d_ws + 9437184);          // 73,728 B

  hipMemsetAsync(out, 0, (size_t)out_size * sizeof(float), stream);
  k_transpose<<<dim3(2304), dim3(256), 0, stream>>>(input, incl);
  k_wconv<<<dim3(64), dim3(576), 0, stream>>>(weight, wbf);
  k_main<<<dim3(1536), dim3(NT), 0, stream>>>(incl, offset, mask, wbf, bias, out);
}

// Round 3
// 148.457 us; speedup vs baseline: 1.0216x; 1.0216x over previous
//
#include <hip/hip_runtime.h>
#include <stdint.h>

#define Hs 96
#define Ws 96
#define HW 9216
#define TILE 96
#define NT 384
#define WROW 296      // padded weight row in halfs (288 + 8)
#define WROWB 592     // bytes

typedef _Float16 h2 __attribute__((ext_vector_type(2)));
typedef _Float16 f16x8 __attribute__((ext_vector_type(8)));
typedef float f32x4 __attribute__((ext_vector_type(4)));

// ---------------- kernel 1: NCHW fp32 -> NHWC fp16 ----------------
__global__ __launch_bounds__(256) void k_transpose(const float* __restrict__ in,
                                                   _Float16* __restrict__ cl) {
  __shared__ _Float16 lt[32 * 68];
  int tid = threadIdx.x;
  int blk = blockIdx.x;
  int xt = blk % 3;
  int r = blk / 3;
  int y = r % Hs;
  int b = r / Hs;
  int x0 = xt * 32;
  {
    int xx = tid & 31, cc = tid >> 5;
    const float* src = in + (size_t)b * 64 * HW + y * Ws + x0 + xx;
#pragma unroll
    for (int i = 0; i < 8; ++i) {
      int c = cc * 8 + i;
      lt[xx * 68 + c] = (_Float16)src[(size_t)c * HW];
    }
  }
  __syncthreads();
  {
    int c4 = tid & 15, pg = tid >> 4;
    _Float16* dst = cl + ((size_t)(b * Hs + y) * Ws + x0) * 64 + c4 * 4;
#pragma unroll
    for (int i = 0; i < 2; ++i) {
      int x = pg * 2 + i;
      *(uint2*)(dst + (size_t)x * 64) = *(const uint2*)(lt + x * 68 + c4 * 4);
    }
  }
}

// ------- kernel 2: weight fp32 [O][C][9] -> fp16 [ck][O][tap*32+c'] -------
__global__ __launch_bounds__(576) void k_wconv(const float* __restrict__ w,
                                               _Float16* __restrict__ wbf) {
  int o = blockIdx.x;
  int r = threadIdx.x;
  int tap = r >> 6, c = r & 63;
  int ck = c >> 5, cc = c & 31;
  wbf[((ck * 64 + o) * 288) + tap * 32 + cc] = (_Float16)w[(o * 64 + c) * 9 + tap];
}

// ---------------- kernel 3: fused sampling + split-K implicit GEMM --------
__device__ __forceinline__ void issue_gathers(const char* inb, uint4 u,
                                              int ckoff, uint4* g) {
  unsigned ax = u.x;
  int a00 = (int)(ax & ~127u) + ckoff;
  int a01 = a00 + ((ax & 1) << 7);
  int a10 = a00 + ((ax & 2) * 6144);
  int a11 = a10 + ((ax & 1) << 7);
  g[0] = *(const uint4*)(inb + a00);
  g[1] = *(const uint4*)(inb + a01);
  g[2] = *(const uint4*)(inb + a10);
  g[3] = *(const uint4*)(inb + a11);
}

__global__ __launch_bounds__(384, 5) void k_main(
    const _Float16* __restrict__ incl, const float* __restrict__ off,
    const float* __restrict__ msk, const _Float16* __restrict__ wbf,
    const float* __restrict__ bias, float* __restrict__ out) {
  __shared__ _Float16 wlds[64 * WROW];   // 37,888 B
  __shared__ uint4 preU[9 * TILE];       // 13,824 B

  int tid = threadIdx.x;
  int blk = blockIdx.x;
  int ck = (blk >= 768) ? 1 : 0;
  int rb0 = blk - (ck ? 768 : 0);
  int b = rb0 & 7;                 // XCD swizzle
  int q0 = (rb0 >> 3) * TILE;

  // phase 0: this ck-half's weights -> LDS
  {
    const char* src = (const char*)wbf + ck * 36864;
    char* dst = (char*)wlds;
#pragma unroll
    for (int i = tid; i < 2304; i += NT) {
      int row = i / 36, s = i - row * 36;
      *(uint4*)(dst + row * WROWB + s * 16) = *(const uint4*)(src + row * 576 + s * 16);
    }
  }

  // phase 1: per-(pixel,tap) packed corner address + bilinear weights
  for (int i = tid; i < 9 * TILE; i += NT) {
    int t = i / TILE, p = i - t * TILE;
    int q = q0 + p;
    int qy = q / 96, qx = q - qy * 96;
    int ty = t / 3, tx = t - ty * 3;
    float dy = off[(size_t)(b * 18 + 2 * t) * HW + q];
    float dx = off[(size_t)(b * 18 + 2 * t + 1) * HW + q];
    float mv = msk[(size_t)(b * 9 + t) * HW + q];
    float yf = (float)(qy - 1 + ty) + dy;
    float xf = (float)(qx - 1 + tx) + dx;
    float y0f = floorf(yf), x0f = floorf(xf);
    float wy = yf - y0f, wx = xf - x0f;
    int y0 = (int)y0f, x0i = (int)x0f;
    int y1 = y0 + 1, x1 = x0i + 1;
    bool yv0 = (y0 >= 0) && (y0 < Hs);
    bool yv1 = (y1 >= 0) && (y1 < Hs);
    bool xv0 = (x0i >= 0) && (x0i < Ws);
    bool xv1 = (x1 >= 0) && (x1 < Ws);
    int y0c = min(max(y0, 0), Hs - 1), y1c = min(max(y1, 0), Hs - 1);
    int x0c = min(max(x0i, 0), Ws - 1), x1c = min(max(x1, 0), Ws - 1);
    unsigned a00 = (unsigned)(b * HW + y0c * 96 + x0c) * 128u;
    unsigned fdx = (unsigned)(x1c - x0c);
    unsigned fdy = (unsigned)(y1c - y0c);
    float omy = 1.f - wy, omx = 1.f - wx;
    float f00 = omy * omx * mv * ((yv0 && xv0) ? 1.f : 0.f);
    float f01 = omy * wx  * mv * ((yv0 && xv1) ? 1.f : 0.f);
    float f10 = wy  * omx * mv * ((yv1 && xv0) ? 1.f : 0.f);
    float f11 = wy  * wx  * mv * ((yv1 && xv1) ? 1.f : 0.f);
    uint4 u;
    u.x = a00 | fdx | (fdy << 1);
    u.y = __builtin_bit_cast(unsigned, __builtin_amdgcn_cvt_pkrtz(f00, f01));
    u.z = __builtin_bit_cast(unsigned, __builtin_amdgcn_cvt_pkrtz(f10, f11));
    u.w = 0;
    preU[i] = u;
  }
  __syncthreads();

  // phase 2: depth-2 software-pipelined gather + interp + MFMA
  int lane = tid & 63;
  int wid = tid >> 6;
  int n = lane & 15;
  int quad16 = (lane >> 4) * 16;
  int p = wid * 16 + n;
  int ckoff = ck * 64 + quad16;
  const char* inb = (const char*)incl;
  const char* wb = (const char*)wlds + n * WROWB + quad16;

  f32x4 acc[4];
#pragma unroll
  for (int mt = 0; mt < 4; ++mt) {
    f32x4 z = {0.f, 0.f, 0.f, 0.f};
    acc[mt] = z;
  }

  uint4 g[2][4];
  uint4 us[2];
  us[0] = preU[p];
  issue_gathers(inb, us[0], ckoff, g[0]);
  us[1] = preU[TILE + p];
  issue_gathers(inb, us[1], ckoff, g[1]);

#pragma unroll
  for (int t = 0; t < 9; ++t) {
    const int cur = t & 1;
    uint4 u = us[cur];
    uint4 g00 = g[cur][0], g01 = g[cur][1], g10 = g[cur][2], g11 = g[cur][3];
    h2 w00 = __builtin_bit_cast(h2, __builtin_amdgcn_perm(u.y, u.y, 0x01000100u));
    h2 w01 = __builtin_bit_cast(h2, __builtin_amdgcn_perm(u.y, u.y, 0x03020302u));
    h2 w10 = __builtin_bit_cast(h2, __builtin_amdgcn_perm(u.z, u.z, 0x01000100u));
    h2 w11 = __builtin_bit_cast(h2, __builtin_amdgcn_perm(u.z, u.z, 0x03020302u));
    union { unsigned u[4]; f16x8 v; } bf;
    bf.u[0] = __builtin_bit_cast(unsigned,
        (h2)(w00 * __builtin_bit_cast(h2, g00.x) + w01 * __builtin_bit_cast(h2, g01.x) +
             w10 * __builtin_bit_cast(h2, g10.x) + w11 * __builtin_bit_cast(h2, g11.x)));
    bf.u[1] = __builtin_bit_cast(unsigned,
        (h2)(w00 * __builtin_bit_cast(h2, g00.y) + w01 * __builtin_bit_cast(h2, g01.y) +
             w10 * __builtin_bit_cast(h2, g10.y) + w11 * __builtin_bit_cast(h2, g11.y)));
    bf.u[2] = __builtin_bit_cast(unsigned,
        (h2)(w00 * __builtin_bit_cast(h2, g00.z) + w01 * __builtin_bit_cast(h2, g01.z) +
             w10 * __builtin_bit_cast(h2, g10.z) + w11 * __builtin_bit_cast(h2, g11.z)));
    bf.u[3] = __builtin_bit_cast(unsigned,
        (h2)(w00 * __builtin_bit_cast(h2, g00.w) + w01 * __builtin_bit_cast(h2, g01.w) +
             w10 * __builtin_bit_cast(h2, g10.w) + w11 * __builtin_bit_cast(h2, g11.w)));
    // issue tap t+2's gathers now — consumed two iterations later
    if (t + 2 < 9) {
      us[cur] = preU[(t + 2) * TILE + p];
      issue_gathers(inb, us[cur], ckoff, g[cur]);
    }
    const char* wrow = wb + t * 64;
#pragma unroll
    for (int mt = 0; mt < 4; ++mt) {
      f16x8 af = *(const f16x8*)(wrow + mt * (16 * WROWB));
      acc[mt] = __builtin_amdgcn_mfma_f32_16x16x32_f16(af, bf.v, acc[mt], 0, 0, 0);
    }
  }

  // epilogue: atomic accumulate the two K-halves; ck=0 carries the bias
  int pix = q0 + p;
  float* op = out + (size_t)b * 64 * HW + pix;
  int mrow = quad16 >> 2;
#pragma unroll
  for (int mt = 0; mt < 4; ++mt) {
#pragma unroll
    for (int r = 0; r < 4; ++r) {
      int m = mt * 16 + mrow + r;
      float v = acc[mt][r];
      if (ck == 0) v += bias[m];
      unsafeAtomicAdd(op + (size_t)m * HW, v);
    }
  }
}

extern "C" void kernel_launch(void* const* d_in, const int* in_sizes, int n_in,
                              void* d_out, int out_size, void* d_ws, size_t ws_size,
                              hipStream_t stream) {
  const float* input = (const float*)d_in[0];
  const float* offset = (const float*)d_in[1];
  const float* mask = (const float*)d_in[2];
  const float* weight = (const float*)d_in[3];
  const float* bias = (const float*)d_in[4];
  float* out = (float*)d_out;

  _Float16* incl = (_Float16*)d_ws;
  _Float16* wbf = (_Float16*)((char*)d_ws + 9437184);

  hipMemsetAsync(out, 0, (size_t)out_size * sizeof(float), stream);
  k_transpose<<<dim3(2304), dim3(256), 0, stream>>>(input, incl);
  k_wconv<<<dim3(64), dim3(576), 0, stream>>>(weight, wbf);
  k_main<<<dim3(1536), dim3(NT), 0, stream>>>(incl, offset, mask, wbf, bias, out);
}

// Round 4
// 146.300 us; speedup vs baseline: 1.0367x; 1.0147x over previous
//
#include <hip/hip_runtime.h>
#include <stdint.h>

#define Hs 96
#define Ws 96
#define HW 9216
#define NPIX 73728   // 8 * 9216, GEMM N dimension

typedef _Float16 h2 __attribute__((ext_vector_type(2)));
typedef _Float16 f16x8 __attribute__((ext_vector_type(8)));
typedef float f32x4 __attribute__((ext_vector_type(4)));

__device__ __forceinline__ unsigned interp4(h2 w00, h2 w01, h2 w10, h2 w11,
                                            unsigned a, unsigned bq, unsigned c,
                                            unsigned d) {
  h2 r = w00 * __builtin_bit_cast(h2, a) + w01 * __builtin_bit_cast(h2, bq) +
         w10 * __builtin_bit_cast(h2, c) + w11 * __builtin_bit_cast(h2, d);
  return __builtin_bit_cast(unsigned, r);
}

// ---------------- kernel 1: NCHW fp32 -> NHWC fp16 ----------------
__global__ __launch_bounds__(256) void k_transpose(const float* __restrict__ in,
                                                   _Float16* __restrict__ cl) {
  __shared__ _Float16 lt[32 * 68];
  int tid = threadIdx.x;
  int blk = blockIdx.x;
  int xt = blk % 3;
  int r = blk / 3;
  int y = r % Hs;
  int b = r / Hs;
  int x0 = xt * 32;
  {
    int xx = tid & 31, cc = tid >> 5;
    const float* src = in + (size_t)b * 64 * HW + y * Ws + x0 + xx;
#pragma unroll
    for (int i = 0; i < 8; ++i) {
      int c = cc * 8 + i;
      lt[xx * 68 + c] = (_Float16)src[(size_t)c * HW];
    }
  }
  __syncthreads();
  {
    int c4 = tid & 15, pg = tid >> 4;
    _Float16* dst = cl + ((size_t)(b * Hs + y) * Ws + x0) * 64 + c4 * 4;
#pragma unroll
    for (int i = 0; i < 2; ++i) {
      int x = pg * 2 + i;
      *(uint2*)(dst + (size_t)x * 64) = *(const uint2*)(lt + x * 68 + c4 * 4);
    }
  }
}

// ---- kernel 2: weight fp32 [O][C][9] -> fp16 planes Wg[t*8+c8][o][8ch] ----
__global__ __launch_bounds__(576) void k_wconv(const float* __restrict__ w,
                                               _Float16* __restrict__ wg) {
  int o = blockIdx.x;    // 64
  int r = threadIdx.x;   // 576
  int t = r >> 6, c = r & 63;
  wg[((size_t)(t * 8 + (c >> 3)) * 64 + o) * 8 + (c & 7)] =
      (_Float16)w[(o * 64 + c) * 9 + t];
}

// ---- kernel 3: bilinear sampling -> V planes [t*8+chunk][n= b*9216+q]x16B --
__global__ __launch_bounds__(576) void k_sample(
    const _Float16* __restrict__ incl, const float* __restrict__ off,
    const float* __restrict__ msk, _Float16* __restrict__ V) {
  int lane = threadIdx.x & 63;
  int t = threadIdx.x >> 6;          // wave = tap, 0..8
  int b = blockIdx.x & 7;            // XCD swizzle: image b on XCD b
  int qg = blockIdx.x >> 3;          // 0..143
  int q = qg * 64 + lane;
  int qy = (int)(((unsigned)q * 43691u) >> 22);   // q/96 for q<9216
  int qx = q - qy * 96;
  int ty = t / 3, tx = t - ty * 3;

  float dy = off[(size_t)(b * 18 + 2 * t) * HW + q];
  float dx = off[(size_t)(b * 18 + 2 * t + 1) * HW + q];
  float mv = msk[(size_t)(b * 9 + t) * HW + q];
  float yf = (float)(qy - 1 + ty) + dy;
  float xf = (float)(qx - 1 + tx) + dx;
  float y0f = floorf(yf), x0f = floorf(xf);
  float wy = yf - y0f, wx = xf - x0f;
  int y0 = (int)y0f, x0i = (int)x0f;
  int y1 = y0 + 1, x1 = x0i + 1;
  bool yv0 = (y0 >= 0) && (y0 < Hs);
  bool yv1 = (y1 >= 0) && (y1 < Hs);
  bool xv0 = (x0i >= 0) && (x0i < Ws);
  bool xv1 = (x1 >= 0) && (x1 < Ws);
  int y0c = min(max(y0, 0), Hs - 1), y1c = min(max(y1, 0), Hs - 1);
  int x0c = min(max(x0i, 0), Ws - 1), x1c = min(max(x1, 0), Ws - 1);
  float omy = 1.f - wy, omx = 1.f - wx;
  float f00 = omy * omx * mv * ((yv0 && xv0) ? 1.f : 0.f);
  float f01 = omy * wx  * mv * ((yv0 && xv1) ? 1.f : 0.f);
  float f10 = wy  * omx * mv * ((yv1 && xv0) ? 1.f : 0.f);
  float f11 = wy  * wx  * mv * ((yv1 && xv1) ? 1.f : 0.f);
  _Float16 h00 = (_Float16)f00, h01 = (_Float16)f01;
  _Float16 h10 = (_Float16)f10, h11 = (_Float16)f11;
  h2 w00 = {h00, h00}, w01 = {h01, h01}, w10 = {h10, h10}, w11 = {h11, h11};

  const char* r00 = (const char*)incl + (size_t)(b * HW + y0c * 96 + x0c) * 128;
  const char* r01 = (const char*)incl + (size_t)(b * HW + y0c * 96 + x1c) * 128;
  const char* r10 = (const char*)incl + (size_t)(b * HW + y1c * 96 + x0c) * 128;
  const char* r11 = (const char*)incl + (size_t)(b * HW + y1c * 96 + x1c) * 128;
  char* vp = (char*)V + ((size_t)(t * 8) * NPIX + (size_t)b * HW + q) * 16;

#pragma unroll
  for (int c = 0; c < 8; ++c) {
    uint4 g00 = *(const uint4*)(r00 + c * 16);
    uint4 g01 = *(const uint4*)(r01 + c * 16);
    uint4 g10 = *(const uint4*)(r10 + c * 16);
    uint4 g11 = *(const uint4*)(r11 + c * 16);
    uint4 o;
    o.x = interp4(w00, w01, w10, w11, g00.x, g01.x, g10.x, g11.x);
    o.y = interp4(w00, w01, w10, w11, g00.y, g01.y, g10.y, g11.y);
    o.z = interp4(w00, w01, w10, w11, g00.z, g01.z, g10.z, g11.z);
    o.w = interp4(w00, w01, w10, w11, g00.w, g01.w, g10.w, g11.w);
    *(uint4*)(vp + (size_t)c * (NPIX * 16)) = o;
  }
}

// ---- kernel 4: GEMM  out[b][m][q] = sum_k Wg[k][m] * V[k][n],  K=576 ------
__global__ __launch_bounds__(256) void k_gemm(
    const _Float16* __restrict__ Wg, const _Float16* __restrict__ V,
    const float* __restrict__ bias, float* __restrict__ out) {
  __shared__ uint4 Ab[2][4 * 64];    // 4 KB per buf
  __shared__ uint4 Bb[2][4 * 128];   // 8 KB per buf

  int tid = threadIdx.x;
  int blk = blockIdx.x;
  int b = blk & 7;                   // XCD swizzle
  int qt = blk >> 3;                 // 0..71
  size_t n0 = (size_t)b * HW + qt * 128;

  const uint4* Au = (const uint4*)Wg;   // plane p: Au[p*64 + m]
  const uint4* Vu = (const uint4*)V;    // plane p: Vu[p*NPIX + n]

  int sp_a = tid >> 6, sm_a = tid & 63;
  int sp_b0 = tid >> 7, sn_b0 = tid & 127;
  int sp_b1 = 2 + sp_b0, sn_b1 = sn_b0;

  uint4 ra, rb0, rb1;

  int lane = tid & 63, wv = tid >> 6;
  int n16 = lane & 15, q4 = lane >> 4;

  f32x4 acc[4][2];
#pragma unroll
  for (int mt = 0; mt < 4; ++mt)
#pragma unroll
    for (int j = 0; j < 2; ++j) {
      f32x4 z = {0.f, 0.f, 0.f, 0.f};
      acc[mt][j] = z;
    }

  // prologue
  ra = Au[(size_t)sp_a * 64 + sm_a];
  rb0 = Vu[(size_t)sp_b0 * NPIX + n0 + sn_b0];
  rb1 = Vu[(size_t)sp_b1 * NPIX + n0 + sn_b1];
  Ab[0][sp_a * 64 + sm_a] = ra;
  Bb[0][sp_b0 * 128 + sn_b0] = rb0;
  Bb[0][sp_b1 * 128 + sn_b1] = rb1;
  __syncthreads();

  for (int kc = 0; kc < 18; ++kc) {
    int buf = kc & 1;
    if (kc < 17) {
      int kp = (kc + 1) * 4;
      ra = Au[(size_t)(kp + sp_a) * 64 + sm_a];
      rb0 = Vu[(size_t)(kp + sp_b0) * NPIX + n0 + sn_b0];
      rb1 = Vu[(size_t)(kp + sp_b1) * NPIX + n0 + sn_b1];
    }
    f16x8 afr[4], bfr[2];
#pragma unroll
    for (int mt = 0; mt < 4; ++mt)
      afr[mt] = __builtin_bit_cast(f16x8, Ab[buf][q4 * 64 + mt * 16 + n16]);
#pragma unroll
    for (int j = 0; j < 2; ++j)
      bfr[j] = __builtin_bit_cast(f16x8, Bb[buf][q4 * 128 + wv * 32 + j * 16 + n16]);
#pragma unroll
    for (int mt = 0; mt < 4; ++mt)
#pragma unroll
      for (int j = 0; j < 2; ++j)
        acc[mt][j] = __builtin_amdgcn_mfma_f32_16x16x32_f16(afr[mt], bfr[j],
                                                            acc[mt][j], 0, 0, 0);
    __syncthreads();
    if (kc < 17) {
      int nb = buf ^ 1;
      Ab[nb][sp_a * 64 + sm_a] = ra;
      Bb[nb][sp_b0 * 128 + sn_b0] = rb0;
      Bb[nb][sp_b1 * 128 + sn_b1] = rb1;
      __syncthreads();
    }
  }

  // epilogue: D col = n (pixel), row m = quad*4 + reg
#pragma unroll
  for (int mt = 0; mt < 4; ++mt)
#pragma unroll
    for (int j = 0; j < 2; ++j) {
      int col = qt * 128 + wv * 32 + j * 16 + n16;
#pragma unroll
      for (int r = 0; r < 4; ++r) {
        int m = mt * 16 + q4 * 4 + r;
        out[(size_t)(b * 64 + m) * HW + col] = acc[mt][j][r] + bias[m];
      }
    }
}

extern "C" void kernel_launch(void* const* d_in, const int* in_sizes, int n_in,
                              void* d_out, int out_size, void* d_ws, size_t ws_size,
                              hipStream_t stream) {
  const float* input = (const float*)d_in[0];
  const float* offset = (const float*)d_in[1];
  const float* mask = (const float*)d_in[2];
  const float* weight = (const float*)d_in[3];
  const float* bias = (const float*)d_in[4];
  float* out = (float*)d_out;

  _Float16* incl = (_Float16*)d_ws;                              // 9,437,184 B
  _Float16* wg = (_Float16*)((char*)d_ws + 9437184);             // 73,728 B
  _Float16* V = (_Float16*)((char*)d_ws + 9510912);              // 84,934,656 B

  k_transpose<<<dim3(2304), dim3(256), 0, stream>>>(input, incl);
  k_wconv<<<dim3(64), dim3(576), 0, stream>>>(weight, wg);
  k_sample<<<dim3(1152), dim3(576), 0, stream>>>(incl, offset, mask, V);
  k_gemm<<<dim3(576), dim3(256), 0, stream>>>(wg, V, bias, out);
}

// Round 6
// 125.880 us; speedup vs baseline: 1.2049x; 1.1622x over previous
//
#include <hip/hip_runtime.h>
#include <stdint.h>

#define Hs 96
#define Ws 96
#define HW 9216
#define NPIX 73728   // 8 * 9216, GEMM N dimension

typedef _Float16 h2 __attribute__((ext_vector_type(2)));
typedef _Float16 f16x8 __attribute__((ext_vector_type(8)));
typedef float f32x4 __attribute__((ext_vector_type(4)));

__device__ __forceinline__ unsigned interp4(h2 w00, h2 w01, h2 w10, h2 w11,
                                            unsigned a, unsigned bq, unsigned c,
                                            unsigned d) {
  h2 r = w00 * __builtin_bit_cast(h2, a) + w01 * __builtin_bit_cast(h2, bq) +
         w10 * __builtin_bit_cast(h2, c) + w11 * __builtin_bit_cast(h2, d);
  return __builtin_bit_cast(unsigned, r);
}

// ---------------- kernel 1: NCHW fp32 -> NHWC fp16 ----------------
__global__ __launch_bounds__(256) void k_transpose(const float* __restrict__ in,
                                                   _Float16* __restrict__ cl) {
  __shared__ _Float16 lt[32 * 68];
  int tid = threadIdx.x;
  int blk = blockIdx.x;
  int xt = blk % 3;
  int r = blk / 3;
  int y = r % Hs;
  int b = r / Hs;
  int x0 = xt * 32;
  {
    int xx = tid & 31, cc = tid >> 5;
    const float* src = in + (size_t)b * 64 * HW + y * Ws + x0 + xx;
#pragma unroll
    for (int i = 0; i < 8; ++i) {
      int c = cc * 8 + i;
      lt[xx * 68 + c] = (_Float16)src[(size_t)c * HW];
    }
  }
  __syncthreads();
  {
    int c4 = tid & 15, pg = tid >> 4;
    _Float16* dst = cl + ((size_t)(b * Hs + y) * Ws + x0) * 64 + c4 * 4;
#pragma unroll
    for (int i = 0; i < 2; ++i) {
      int x = pg * 2 + i;
      *(uint2*)(dst + (size_t)x * 64) = *(const uint2*)(lt + x * 68 + c4 * 4);
    }
  }
}

// ---- kernel 2: weight fp32 [O][C][9] -> fp16 planes Wg[t*8+c8][o][8ch] ----
__global__ __launch_bounds__(576) void k_wconv(const float* __restrict__ w,
                                               _Float16* __restrict__ wg) {
  int o = blockIdx.x;    // 64
  int r = threadIdx.x;   // 576
  int t = r >> 6, c = r & 63;
  wg[((size_t)(t * 8 + (c >> 3)) * 64 + o) * 8 + (c & 7)] =
      (_Float16)w[(o * 64 + c) * 9 + t];
}

// ---- kernel 3: bilinear sampling, cooperative 8-lane row gathers ----------
// Block: 256 threads, 32 pixels x 9 taps. Group of 8 lanes <-> one pixel;
// lane j handles channel chunk j (16B of the 128B NHWC row).
// Grid: 2304 = 8 images (blk&7, XCD swizzle) x 288 pixel-tiles (blk>>3).
__global__ __launch_bounds__(256, 6) void k_sample(
    const _Float16* __restrict__ incl, const float* __restrict__ off,
    const float* __restrict__ msk, _Float16* __restrict__ V) {
  __shared__ uint4 preU[288];   // 4,608 B: {a00|dx|dy<<1, w00w01, w10w11, -}

  int tid = threadIdx.x;
  int blk = blockIdx.x;
  int b = blk & 7;              // XCD swizzle: image b on XCD b
  int q0 = (blk >> 3) * 32;     // 288 pixel-tiles per image (blk>>3 in 0..287)

  // phase 1: per-(pixel,tap) packed corner address + bilinear weights
  for (int i = tid; i < 288; i += 256) {
    int t = i >> 5, p = i & 31;
    int q = q0 + p;
    int qy = (int)(((unsigned)q * 43691u) >> 22);   // q/96 for q<9216
    int qx = q - qy * 96;
    int ty = t / 3, tx = t - ty * 3;
    float dy = off[(size_t)(b * 18 + 2 * t) * HW + q];
    float dx = off[(size_t)(b * 18 + 2 * t + 1) * HW + q];
    float mv = msk[(size_t)(b * 9 + t) * HW + q];
    float yf = (float)(qy - 1 + ty) + dy;
    float xf = (float)(qx - 1 + tx) + dx;
    float y0f = floorf(yf), x0f = floorf(xf);
    float wy = yf - y0f, wx = xf - x0f;
    int y0 = (int)y0f, x0i = (int)x0f;
    int y1 = y0 + 1, x1 = x0i + 1;
    bool yv0 = (y0 >= 0) && (y0 < Hs);
    bool yv1 = (y1 >= 0) && (y1 < Hs);
    bool xv0 = (x0i >= 0) && (x0i < Ws);
    bool xv1 = (x1 >= 0) && (x1 < Ws);
    int y0c = min(max(y0, 0), Hs - 1), y1c = min(max(y1, 0), Hs - 1);
    int x0c = min(max(x0i, 0), Ws - 1), x1c = min(max(x1, 0), Ws - 1);
    float omy = 1.f - wy, omx = 1.f - wx;
    float f00 = omy * omx * mv * ((yv0 && xv0) ? 1.f : 0.f);
    float f01 = omy * wx  * mv * ((yv0 && xv1) ? 1.f : 0.f);
    float f10 = wy  * omx * mv * ((yv1 && xv0) ? 1.f : 0.f);
    float f11 = wy  * wx  * mv * ((yv1 && xv1) ? 1.f : 0.f);
    uint4 u;
    u.x = ((unsigned)(b * HW + y0c * 96 + x0c) * 128u) |
          (unsigned)(x1c - x0c) | ((unsigned)(y1c - y0c) << 1);
    u.y = __builtin_bit_cast(unsigned, __builtin_amdgcn_cvt_pkrtz(f00, f01));
    u.z = __builtin_bit_cast(unsigned, __builtin_amdgcn_cvt_pkrtz(f10, f11));
    u.w = 0;
    preU[i] = u;
  }
  __syncthreads();

  // phase 2: group g (8 lanes) <-> pixel q0+g; lane j <-> chunk j
  int j = tid & 7;
  int g = tid >> 3;            // 0..31
  const char* inb = (const char*)incl;
  char* vbase = (char*)V + ((size_t)b * HW + q0 + g) * 16;

#pragma unroll
  for (int t = 0; t < 9; ++t) {
    uint4 u = preU[t * 32 + g];          // same addr across group -> broadcast
    unsigned ax = u.x;
    int a00 = (int)(ax & ~127u) + j * 16;
    int a01 = a00 + ((ax & 1) << 7);
    int a10 = a00 + ((ax & 2) * 6144);
    int a11 = a10 + ((ax & 1) << 7);
    h2 w00 = __builtin_bit_cast(h2, __builtin_amdgcn_perm(u.y, u.y, 0x01000100u));
    h2 w01 = __builtin_bit_cast(h2, __builtin_amdgcn_perm(u.y, u.y, 0x03020302u));
    h2 w10 = __builtin_bit_cast(h2, __builtin_amdgcn_perm(u.z, u.z, 0x01000100u));
    h2 w11 = __builtin_bit_cast(h2, __builtin_amdgcn_perm(u.z, u.z, 0x03020302u));
    uint4 g00 = *(const uint4*)(inb + a00);
    uint4 g01 = *(const uint4*)(inb + a01);
    uint4 g10 = *(const uint4*)(inb + a10);
    uint4 g11 = *(const uint4*)(inb + a11);
    uint4 o;
    o.x = interp4(w00, w01, w10, w11, g00.x, g01.x, g10.x, g11.x);
    o.y = interp4(w00, w01, w10, w11, g00.y, g01.y, g10.y, g11.y);
    o.z = interp4(w00, w01, w10, w11, g00.z, g01.z, g10.z, g11.z);
    o.w = interp4(w00, w01, w10, w11, g00.w, g01.w, g10.w, g11.w);
    *(uint4*)(vbase + (size_t)(t * 8 + j) * (NPIX * 16)) = o;
  }
}

// ---- kernel 4: GEMM  out[b][m][q] = sum_k Wg[k][m] * V[k][n],  K=576 ------
__global__ __launch_bounds__(256) void k_gemm(
    const _Float16* __restrict__ Wg, const _Float16* __restrict__ V,
    const float* __restrict__ bias, float* __restrict__ out) {
  __shared__ uint4 Ab[2][4 * 64];    // 4 KB per buf
  __shared__ uint4 Bb[2][4 * 128];   // 8 KB per buf

  int tid = threadIdx.x;
  int blk = blockIdx.x;
  int b = blk & 7;                   // XCD swizzle
  int qt = blk >> 3;                 // 0..71
  size_t n0 = (size_t)b * HW + qt * 128;

  const uint4* Au = (const uint4*)Wg;   // plane p: Au[p*64 + m]
  const uint4* Vu = (const uint4*)V;    // plane p: Vu[p*NPIX + n]

  int sp_a = tid >> 6, sm_a = tid & 63;
  int sp_b0 = tid >> 7, sn_b0 = tid & 127;
  int sp_b1 = 2 + sp_b0, sn_b1 = sn_b0;

  uint4 ra, rb0, rb1;

  int lane = tid & 63, wv = tid >> 6;
  int n16 = lane & 15, q4 = lane >> 4;

  f32x4 acc[4][2];
#pragma unroll
  for (int mt = 0; mt < 4; ++mt)
#pragma unroll
    for (int jj = 0; jj < 2; ++jj) {
      f32x4 z = {0.f, 0.f, 0.f, 0.f};
      acc[mt][jj] = z;
    }

  // prologue
  ra = Au[(size_t)sp_a * 64 + sm_a];
  rb0 = Vu[(size_t)sp_b0 * NPIX + n0 + sn_b0];
  rb1 = Vu[(size_t)sp_b1 * NPIX + n0 + sn_b1];
  Ab[0][sp_a * 64 + sm_a] = ra;
  Bb[0][sp_b0 * 128 + sn_b0] = rb0;
  Bb[0][sp_b1 * 128 + sn_b1] = rb1;
  __syncthreads();

  for (int kc = 0; kc < 18; ++kc) {
    int buf = kc & 1;
    if (kc < 17) {
      int kp = (kc + 1) * 4;
      ra = Au[(size_t)(kp + sp_a) * 64 + sm_a];
      rb0 = Vu[(size_t)(kp + sp_b0) * NPIX + n0 + sn_b0];
      rb1 = Vu[(size_t)(kp + sp_b1) * NPIX + n0 + sn_b1];
    }
    f16x8 afr[4], bfr[2];
#pragma unroll
    for (int mt = 0; mt < 4; ++mt)
      afr[mt] = __builtin_bit_cast(f16x8, Ab[buf][q4 * 64 + mt * 16 + n16]);
#pragma unroll
    for (int jj = 0; jj < 2; ++jj)
      bfr[jj] = __builtin_bit_cast(f16x8, Bb[buf][q4 * 128 + wv * 32 + jj * 16 + n16]);
#pragma unroll
    for (int mt = 0; mt < 4; ++mt)
#pragma unroll
      for (int jj = 0; jj < 2; ++jj)
        acc[mt][jj] = __builtin_amdgcn_mfma_f32_16x16x32_f16(afr[mt], bfr[jj],
                                                             acc[mt][jj], 0, 0, 0);
    __syncthreads();
    if (kc < 17) {
      int nb = buf ^ 1;
      Ab[nb][sp_a * 64 + sm_a] = ra;
      Bb[nb][sp_b0 * 128 + sn_b0] = rb0;
      Bb[nb][sp_b1 * 128 + sn_b1] = rb1;
      __syncthreads();
    }
  }

  // epilogue: D col = n (pixel), row m = quad*4 + reg
#pragma unroll
  for (int mt = 0; mt < 4; ++mt)
#pragma unroll
    for (int jj = 0; jj < 2; ++jj) {
      int col = qt * 128 + wv * 32 + jj * 16 + n16;
#pragma unroll
      for (int r = 0; r < 4; ++r) {
        int m = mt * 16 + q4 * 4 + r;
        out[(size_t)(b * 64 + m) * HW + col] = acc[mt][jj][r] + bias[m];
      }
    }
}

extern "C" void kernel_launch(void* const* d_in, const int* in_sizes, int n_in,
                              void* d_out, int out_size, void* d_ws, size_t ws_size,
                              hipStream_t stream) {
  const float* input = (const float*)d_in[0];
  const float* offset = (const float*)d_in[1];
  const float* mask = (const float*)d_in[2];
  const float* weight = (const float*)d_in[3];
  const float* bias = (const float*)d_in[4];
  float* out = (float*)d_out;

  _Float16* incl = (_Float16*)d_ws;                              // 9,437,184 B
  _Float16* wg = (_Float16*)((char*)d_ws + 9437184);             // 73,728 B
  _Float16* V = (_Float16*)((char*)d_ws + 9510912);              // 84,934,656 B

  k_transpose<<<dim3(2304), dim3(256), 0, stream>>>(input, incl);
  k_wconv<<<dim3(64), dim3(576), 0, stream>>>(weight, wg);
  k_sample<<<dim3(2304), dim3(256), 0, stream>>>(incl, offset, mask, V);
  k_gemm<<<dim3(576), dim3(256), 0, stream>>>(wg, V, bias, out);
}

// Round 7
// 108.818 us; speedup vs baseline: 1.3938x; 1.1568x over previous
//
#include <hip/hip_runtime.h>
#include <stdint.h>

#define Hs 96
#define Ws 96
#define HW 9216

typedef _Float16 h2 __attribute__((ext_vector_type(2)));
typedef _Float16 f16x8 __attribute__((ext_vector_type(8)));
typedef float f32x4 __attribute__((ext_vector_type(4)));

__device__ __forceinline__ unsigned interp4(h2 w00, h2 w01, h2 w10, h2 w11,
                                            unsigned a, unsigned bq, unsigned c,
                                            unsigned d) {
  h2 r = w00 * __builtin_bit_cast(h2, a) + w01 * __builtin_bit_cast(h2, bq) +
         w10 * __builtin_bit_cast(h2, c) + w11 * __builtin_bit_cast(h2, d);
  return __builtin_bit_cast(unsigned, r);
}

// ---------------- kernel 1: NCHW fp32 -> NHWC fp16 ----------------
__global__ __launch_bounds__(256) void k_transpose(const float* __restrict__ in,
                                                   _Float16* __restrict__ cl) {
  __shared__ _Float16 lt[32 * 68];
  int tid = threadIdx.x;
  int blk = blockIdx.x;
  int xt = blk % 3;
  int r = blk / 3;
  int y = r % Hs;
  int b = r / Hs;
  int x0 = xt * 32;
  {
    int xx = tid & 31, cc = tid >> 5;
    const float* src = in + (size_t)b * 64 * HW + y * Ws + x0 + xx;
#pragma unroll
    for (int i = 0; i < 8; ++i) {
      int c = cc * 8 + i;
      lt[xx * 68 + c] = (_Float16)src[(size_t)c * HW];
    }
  }
  __syncthreads();
  {
    int c4 = tid & 15, pg = tid >> 4;
    _Float16* dst = cl + ((size_t)(b * Hs + y) * Ws + x0) * 64 + c4 * 4;
#pragma unroll
    for (int i = 0; i < 2; ++i) {
      int x = pg * 2 + i;
      *(uint2*)(dst + (size_t)x * 64) = *(const uint2*)(lt + x * 68 + c4 * 4);
    }
  }
}

// ---- kernel 2: weight fp32 [O][C][9] -> fp16 planes Wg[t*8+c8][o][8ch] ----
__global__ __launch_bounds__(576) void k_wconv(const float* __restrict__ w,
                                               _Float16* __restrict__ wg) {
  int o = blockIdx.x;    // 64
  int r = threadIdx.x;   // 576
  int t = r >> 6, c = r & 63;
  wg[((size_t)(t * 8 + (c >> 3)) * 64 + o) * 8 + (c & 7)] =
      (_Float16)w[(o * 64 + c) * 9 + t];
}

// ---- kernel 3: fused sampling + implicit GEMM, tap-pipelined LDS V-tile ---
// Block: 256 threads, 64 pixels. Grid: 1152 = 8 images (blk&7, XCD swizzle)
// x 144 pixel-tiles. Sampling: group of 8 lanes <-> one pixel, lane j <->
// 16B channel chunk. GEMM: wave wv <-> 16 pixels, full M=64, K=64 per tap.
// V-tile rows padded to 144 B -> only 2-way (free) LDS bank aliasing.
__device__ __forceinline__ void sample_tap(const char* inb,
                                           const unsigned* preA,
                                           const uint2* preW, uint4* vrow,
                                           int t, int g, int j) {
#pragma unroll
  for (int it = 0; it < 2; ++it) {
    int gg = g + it * 32;
    unsigned ax = preA[t * 64 + gg];      // broadcast across the 8-lane group
    uint2 pw = preW[t * 64 + gg];
    int a00 = (int)(ax & ~127u) + j * 16;
    int a01 = a00 + ((ax & 1) << 7);
    int a10 = a00 + ((ax & 2) * 6144);    // +12288 B = one image row
    int a11 = a10 + ((ax & 1) << 7);
    h2 w00 = __builtin_bit_cast(h2, __builtin_amdgcn_perm(pw.x, pw.x, 0x01000100u));
    h2 w01 = __builtin_bit_cast(h2, __builtin_amdgcn_perm(pw.x, pw.x, 0x03020302u));
    h2 w10 = __builtin_bit_cast(h2, __builtin_amdgcn_perm(pw.y, pw.y, 0x01000100u));
    h2 w11 = __builtin_bit_cast(h2, __builtin_amdgcn_perm(pw.y, pw.y, 0x03020302u));
    uint4 g00 = *(const uint4*)(inb + a00);
    uint4 g01 = *(const uint4*)(inb + a01);
    uint4 g10 = *(const uint4*)(inb + a10);
    uint4 g11 = *(const uint4*)(inb + a11);
    uint4 o;
    o.x = interp4(w00, w01, w10, w11, g00.x, g01.x, g10.x, g11.x);
    o.y = interp4(w00, w01, w10, w11, g00.y, g01.y, g10.y, g11.y);
    o.z = interp4(w00, w01, w10, w11, g00.z, g01.z, g10.z, g11.z);
    o.w = interp4(w00, w01, w10, w11, g00.w, g01.w, g10.w, g11.w);
    vrow[gg * 9 + j] = o;
  }
}

__global__ __launch_bounds__(256, 5) void k_fused(
    const _Float16* __restrict__ incl, const float* __restrict__ off,
    const float* __restrict__ msk, const _Float16* __restrict__ wg,
    const float* __restrict__ bias, float* __restrict__ out) {
  __shared__ unsigned preA[576];     // 2,304 B
  __shared__ uint2 preW[576];        // 4,608 B
  __shared__ uint4 Vb[2][64 * 9];    // 18,432 B  (9 uint4 = 144 B per pixel)

  int tid = threadIdx.x;
  int blk = blockIdx.x;
  int b = blk & 7;              // XCD swizzle: image b on XCD b
  int q0 = (blk >> 3) * 64;     // 144 pixel-tiles per image

  // phase pre: per-(pixel,tap) packed corner address + bilinear weights
  for (int i = tid; i < 576; i += 256) {
    int t = i >> 6, p = i & 63;
    int q = q0 + p;
    int qy = (int)(((unsigned)q * 43691u) >> 22);   // q/96 for q<9216
    int qx = q - qy * 96;
    int ty = t / 3, tx = t - ty * 3;
    float dy = off[(size_t)(b * 18 + 2 * t) * HW + q];
    float dx = off[(size_t)(b * 18 + 2 * t + 1) * HW + q];
    float mv = msk[(size_t)(b * 9 + t) * HW + q];
    float yf = (float)(qy - 1 + ty) + dy;
    float xf = (float)(qx - 1 + tx) + dx;
    float y0f = floorf(yf), x0f = floorf(xf);
    float wy = yf - y0f, wx = xf - x0f;
    int y0 = (int)y0f, x0i = (int)x0f;
    int y1 = y0 + 1, x1 = x0i + 1;
    bool yv0 = (y0 >= 0) && (y0 < Hs);
    bool yv1 = (y1 >= 0) && (y1 < Hs);
    bool xv0 = (x0i >= 0) && (x0i < Ws);
    bool xv1 = (x1 >= 0) && (x1 < Ws);
    int y0c = min(max(y0, 0), Hs - 1), y1c = min(max(y1, 0), Hs - 1);
    int x0c = min(max(x0i, 0), Ws - 1), x1c = min(max(x1, 0), Ws - 1);
    float omy = 1.f - wy, omx = 1.f - wx;
    float f00 = omy * omx * mv * ((yv0 && xv0) ? 1.f : 0.f);
    float f01 = omy * wx  * mv * ((yv0 && xv1) ? 1.f : 0.f);
    float f10 = wy  * omx * mv * ((yv1 && xv0) ? 1.f : 0.f);
    float f11 = wy  * wx  * mv * ((yv1 && xv1) ? 1.f : 0.f);
    preA[i] = ((unsigned)(b * HW + y0c * 96 + x0c) * 128u) |
              (unsigned)(x1c - x0c) | ((unsigned)(y1c - y0c) << 1);
    uint2 pw;
    pw.x = __builtin_bit_cast(unsigned, __builtin_amdgcn_cvt_pkrtz(f00, f01));
    pw.y = __builtin_bit_cast(unsigned, __builtin_amdgcn_cvt_pkrtz(f10, f11));
    preW[i] = pw;
  }
  __syncthreads();

  int j = tid & 7;
  int g = tid >> 3;            // 0..31 (sampling group)
  int lane = tid & 63, wv = tid >> 6;
  int n16 = lane & 15, q4 = lane >> 4;
  const char* inb = (const char*)incl;
  const uint4* Ag = (const uint4*)wg;   // plane p: Ag[p*64 + m]

  f32x4 acc[4];
#pragma unroll
  for (int mt = 0; mt < 4; ++mt) {
    f32x4 z = {0.f, 0.f, 0.f, 0.f};
    acc[mt] = z;
  }

  // prologue: sample tap 0 into buf 0
  sample_tap(inb, preA, preW, &Vb[0][0], 0, g, j);
  __syncthreads();

  for (int t = 0; t < 9; ++t) {
    int buf = t & 1;
    if (t < 8)
      sample_tap(inb, preA, preW, &Vb[buf ^ 1][0], t + 1, g, j);
    // GEMM on tap t: K=64 = 2 chunks of 32
#pragma unroll
    for (int kc = 0; kc < 2; ++kc) {
      f16x8 bfr = __builtin_bit_cast(
          f16x8, Vb[buf][(wv * 16 + n16) * 9 + kc * 4 + q4]);
#pragma unroll
      for (int mt = 0; mt < 4; ++mt) {
        f16x8 afr = __builtin_bit_cast(
            f16x8, Ag[(size_t)((t * 8 + kc * 4 + q4) * 64 + mt * 16 + n16)]);
        acc[mt] = __builtin_amdgcn_mfma_f32_16x16x32_f16(afr, bfr, acc[mt],
                                                         0, 0, 0);
      }
    }
    __syncthreads();
  }

  // epilogue: D col = pixel (n), row m = quad*4 + reg
  int colq = q0 + wv * 16 + n16;
  float* op = out + (size_t)b * 64 * HW + colq;
#pragma unroll
  for (int mt = 0; mt < 4; ++mt)
#pragma unroll
    for (int r = 0; r < 4; ++r) {
      int m = mt * 16 + q4 * 4 + r;
      op[(size_t)m * HW] = acc[mt][r] + bias[m];
    }
}

extern "C" void kernel_launch(void* const* d_in, const int* in_sizes, int n_in,
                              void* d_out, int out_size, void* d_ws, size_t ws_size,
                              hipStream_t stream) {
  const float* input = (const float*)d_in[0];
  const float* offset = (const float*)d_in[1];
  const float* mask = (const float*)d_in[2];
  const float* weight = (const float*)d_in[3];
  const float* bias = (const float*)d_in[4];
  float* out = (float*)d_out;

  _Float16* incl = (_Float16*)d_ws;                              // 9,437,184 B
  _Float16* wg = (_Float16*)((char*)d_ws + 9437184);             // 73,728 B

  k_transpose<<<dim3(2304), dim3(256), 0, stream>>>(input, incl);
  k_wconv<<<dim3(64), dim3(576), 0, stream>>>(weight, wg);
  k_fused<<<dim3(1152), dim3(256), 0, stream>>>(incl, offset, mask, wg, bias, out);
}

// Round 8
// 102.121 us; speedup vs baseline: 1.4852x; 1.0656x over previous
//
#include <hip/hip_runtime.h>
#include <stdint.h>

#define Hs 96
#define Ws 96
#define HW 9216

typedef _Float16 h2 __attribute__((ext_vector_type(2)));
typedef _Float16 f16x8 __attribute__((ext_vector_type(8)));
typedef float f32x4 __attribute__((ext_vector_type(4)));

__device__ __forceinline__ unsigned interp4(h2 w00, h2 w01, h2 w10, h2 w11,
                                            unsigned a, unsigned bq, unsigned c,
                                            unsigned d) {
  h2 r = w00 * __builtin_bit_cast(h2, a) + w01 * __builtin_bit_cast(h2, bq) +
         w10 * __builtin_bit_cast(h2, c) + w11 * __builtin_bit_cast(h2, d);
  return __builtin_bit_cast(unsigned, r);
}

// ---------------- kernel 1: NCHW fp32 -> NHWC fp16 ----------------
__global__ __launch_bounds__(256) void k_transpose(const float* __restrict__ in,
                                                   _Float16* __restrict__ cl) {
  __shared__ _Float16 lt[32 * 68];
  int tid = threadIdx.x;
  int blk = blockIdx.x;
  int xt = blk % 3;
  int r = blk / 3;
  int y = r % Hs;
  int b = r / Hs;
  int x0 = xt * 32;
  {
    int xx = tid & 31, cc = tid >> 5;
    const float* src = in + (size_t)b * 64 * HW + y * Ws + x0 + xx;
#pragma unroll
    for (int i = 0; i < 8; ++i) {
      int c = cc * 8 + i;
      lt[xx * 68 + c] = (_Float16)src[(size_t)c * HW];
    }
  }
  __syncthreads();
  {
    int c4 = tid & 15, pg = tid >> 4;
    _Float16* dst = cl + ((size_t)(b * Hs + y) * Ws + x0) * 64 + c4 * 4;
#pragma unroll
    for (int i = 0; i < 2; ++i) {
      int x = pg * 2 + i;
      *(uint2*)(dst + (size_t)x * 64) = *(const uint2*)(lt + x * 68 + c4 * 4);
    }
  }
}

// ---- kernel 2: weight fp32 [O][C][9] -> fp16 planes Wg[t*8+c8][o][8ch] ----
__global__ __launch_bounds__(576) void k_wconv(const float* __restrict__ w,
                                               _Float16* __restrict__ wg) {
  int o = blockIdx.x;    // 64
  int r = threadIdx.x;   // 576
  int t = r >> 6, c = r & 63;
  wg[((size_t)(t * 8 + (c >> 3)) * 64 + o) * 8 + (c & 7)] =
      (_Float16)w[(o * 64 + c) * 9 + t];
}

// ---- kernel 3: fused sampling + implicit GEMM, drain-free tap pipeline ----
// Block: 256 threads, 64 pixels. Grid: 1152 = 8 images (blk&7) x 144 tiles.
// Sampling: 8-lane group <-> pixel, lane j <-> 16B channel chunk.
// GEMM: wave wv owns output channels [wv*16, wv*16+16); per tap it runs
// 4 pixel-groups x 2 K-chunks of MFMA. A-fragments (2/wave/tap) prefetched
// into registers one tap ahead; gathers for tap t+1 issued AFTER the
// barrier so every __syncthreads sees an (almost) empty vm queue.
__global__ __launch_bounds__(256, 4) void k_fused(
    const _Float16* __restrict__ incl, const float* __restrict__ off,
    const float* __restrict__ msk, const _Float16* __restrict__ wg,
    const float* __restrict__ bias, float* __restrict__ out) {
  __shared__ unsigned preA[576];     // 2,304 B
  __shared__ uint2 preW[576];        // 4,608 B
  __shared__ uint4 Vb[2][64 * 9];    // 18,432 B (9 uint4 = 144 B per pixel)

  int tid = threadIdx.x;
  int blk = blockIdx.x;
  int b = blk & 7;              // XCD swizzle: image b on XCD b
  int q0 = (blk >> 3) * 64;     // 144 pixel-tiles per image

  // phase pre: per-(pixel,tap) packed corner address + bilinear weights
  for (int i = tid; i < 576; i += 256) {
    int t = i >> 6, p = i & 63;
    int q = q0 + p;
    int qy = (int)(((unsigned)q * 43691u) >> 22);   // q/96 for q<9216
    int qx = q - qy * 96;
    int ty = t / 3, tx = t - ty * 3;
    float dy = off[(size_t)(b * 18 + 2 * t) * HW + q];
    float dx = off[(size_t)(b * 18 + 2 * t + 1) * HW + q];
    float mv = msk[(size_t)(b * 9 + t) * HW + q];
    float yf = (float)(qy - 1 + ty) + dy;
    float xf = (float)(qx - 1 + tx) + dx;
    float y0f = floorf(yf), x0f = floorf(xf);
    float wy = yf - y0f, wx = xf - x0f;
    int y0 = (int)y0f, x0i = (int)x0f;
    int y1 = y0 + 1, x1 = x0i + 1;
    bool yv0 = (y0 >= 0) && (y0 < Hs);
    bool yv1 = (y1 >= 0) && (y1 < Hs);
    bool xv0 = (x0i >= 0) && (x0i < Ws);
    bool xv1 = (x1 >= 0) && (x1 < Ws);
    int y0c = min(max(y0, 0), Hs - 1), y1c = min(max(y1, 0), Hs - 1);
    int x0c = min(max(x0i, 0), Ws - 1), x1c = min(max(x1, 0), Ws - 1);
    float omy = 1.f - wy, omx = 1.f - wx;
    float f00 = omy * omx * mv * ((yv0 && xv0) ? 1.f : 0.f);
    float f01 = omy * wx  * mv * ((yv0 && xv1) ? 1.f : 0.f);
    float f10 = wy  * omx * mv * ((yv1 && xv0) ? 1.f : 0.f);
    float f11 = wy  * wx  * mv * ((yv1 && xv1) ? 1.f : 0.f);
    preA[i] = ((unsigned)(b * HW + y0c * 96 + x0c) * 128u) |
              (unsigned)(x1c - x0c) | ((unsigned)(y1c - y0c) << 1);
    uint2 pw;
    pw.x = __builtin_bit_cast(unsigned, __builtin_amdgcn_cvt_pkrtz(f00, f01));
    pw.y = __builtin_bit_cast(unsigned, __builtin_amdgcn_cvt_pkrtz(f10, f11));
    preW[i] = pw;
  }
  __syncthreads();

  int j = tid & 7;
  int g = tid >> 3;            // 0..31 (sampling group)
  int lane = tid & 63, wv = tid >> 6;
  int n16 = lane & 15, q4 = lane >> 4;
  const char* inb = (const char*)incl;
  const uint4* Ag = (const uint4*)wg;   // plane p: Ag[p*64 + m]
  int arow = wv * 16 + n16;             // A-operand m index for this lane

  f32x4 acc[4];
#pragma unroll
  for (int pg = 0; pg < 4; ++pg) {
    f32x4 z = {0.f, 0.f, 0.f, 0.f};
    acc[pg] = z;
  }

  uint4 ga[2][4];     // gathers for current tap: 2 pixel-subgroups x 4 corners
  uint4 afn0, afn1;   // prefetched A-fragments (next tap)

#define ISSUE_GATHERS(T)                                                     \
  _Pragma("unroll") for (int it = 0; it < 2; ++it) {                         \
    int gg = g + it * 32;                                                    \
    unsigned ax = preA[(T) * 64 + gg];                                       \
    int a00 = (int)(ax & ~127u) + j * 16;                                    \
    int a01 = a00 + ((ax & 1) << 7);                                         \
    int a10 = a00 + ((ax & 2) * 6144);                                       \
    int a11 = a10 + ((ax & 1) << 7);                                         \
    ga[it][0] = *(const uint4*)(inb + a00);                                  \
    ga[it][1] = *(const uint4*)(inb + a01);                                  \
    ga[it][2] = *(const uint4*)(inb + a10);                                  \
    ga[it][3] = *(const uint4*)(inb + a11);                                  \
  }

  // prologue: tap 0 gathers + tap 0 A-fragments
  ISSUE_GATHERS(0)
  afn0 = Ag[(size_t)((0 + q4) * 64 + arow)];
  afn1 = Ag[(size_t)((4 + q4) * 64 + arow)];

#pragma unroll
  for (int t = 0; t < 9; ++t) {
    int buf = t & 1;
    // interp tap t (consumes ga; hw waits its vmcnt here)
    uint4 v0, v1;
#pragma unroll
    for (int it = 0; it < 2; ++it) {
      int gg = g + it * 32;
      uint2 pw = preW[t * 64 + gg];
      h2 w00 = __builtin_bit_cast(h2, __builtin_amdgcn_perm(pw.x, pw.x, 0x01000100u));
      h2 w01 = __builtin_bit_cast(h2, __builtin_amdgcn_perm(pw.x, pw.x, 0x03020302u));
      h2 w10 = __builtin_bit_cast(h2, __builtin_amdgcn_perm(pw.y, pw.y, 0x01000100u));
      h2 w11 = __builtin_bit_cast(h2, __builtin_amdgcn_perm(pw.y, pw.y, 0x03020302u));
      uint4 r;
      r.x = interp4(w00, w01, w10, w11, ga[it][0].x, ga[it][1].x, ga[it][2].x, ga[it][3].x);
      r.y = interp4(w00, w01, w10, w11, ga[it][0].y, ga[it][1].y, ga[it][2].y, ga[it][3].y);
      r.z = interp4(w00, w01, w10, w11, ga[it][0].z, ga[it][1].z, ga[it][2].z, ga[it][3].z);
      r.w = interp4(w00, w01, w10, w11, ga[it][0].w, ga[it][1].w, ga[it][2].w, ga[it][3].w);
      if (it == 0) v0 = r; else v1 = r;
    }
    uint4 afc0 = afn0, afc1 = afn1;
    Vb[buf][g * 9 + j] = v0;
    Vb[buf][(g + 32) * 9 + j] = v1;
    __syncthreads();   // vm queue ~empty here -> drain is free
    if (t < 8) {
      // issue next tap's loads; consumed before the NEXT barrier
      ISSUE_GATHERS(t + 1)
      afn0 = Ag[(size_t)(((t + 1) * 8 + q4) * 64 + arow)];
      afn1 = Ag[(size_t)(((t + 1) * 8 + 4 + q4) * 64 + arow)];
    }
    // MFMA on tap t: wave wv covers m in [wv*16, wv*16+16), all 64 pixels
#pragma unroll
    for (int pg = 0; pg < 4; ++pg) {
      f16x8 b0 = __builtin_bit_cast(f16x8, Vb[buf][(pg * 16 + n16) * 9 + q4]);
      f16x8 b1 = __builtin_bit_cast(f16x8, Vb[buf][(pg * 16 + n16) * 9 + 4 + q4]);
      acc[pg] = __builtin_amdgcn_mfma_f32_16x16x32_f16(
          __builtin_bit_cast(f16x8, afc0), b0, acc[pg], 0, 0, 0);
      acc[pg] = __builtin_amdgcn_mfma_f32_16x16x32_f16(
          __builtin_bit_cast(f16x8, afc1), b1, acc[pg], 0, 0, 0);
    }
  }
#undef ISSUE_GATHERS

  // epilogue: D col = pixel (n16), row m = wv*16 + q4*4 + r
  int m0 = wv * 16 + q4 * 4;
  float bv[4];
#pragma unroll
  for (int r = 0; r < 4; ++r) bv[r] = bias[m0 + r];
#pragma unroll
  for (int pg = 0; pg < 4; ++pg) {
    int col = q0 + pg * 16 + n16;
    float* op = out + (size_t)b * 64 * HW + col;
#pragma unroll
    for (int r = 0; r < 4; ++r)
      op[(size_t)(m0 + r) * HW] = acc[pg][r] + bv[r];
  }
}

extern "C" void kernel_launch(void* const* d_in, const int* in_sizes, int n_in,
                              void* d_out, int out_size, void* d_ws, size_t ws_size,
                              hipStream_t stream) {
  const float* input = (const float*)d_in[0];
  const float* offset = (const float*)d_in[1];
  const float* mask = (const float*)d_in[2];
  const float* weight = (const float*)d_in[3];
  const float* bias = (const float*)d_in[4];
  float* out = (float*)d_out;

  _Float16* incl = (_Float16*)d_ws;                              // 9,437,184 B
  _Float16* wg = (_Float16*)((char*)d_ws + 9437184);             // 73,728 B

  k_transpose<<<dim3(2304), dim3(256), 0, stream>>>(input, incl);
  k_wconv<<<dim3(64), dim3(576), 0, stream>>>(weight, wg);
  k_fused<<<dim3(1152), dim3(256), 0, stream>>>(incl, offset, mask, wg, bias, out);
}

// Round 9
// 100.627 us; speedup vs baseline: 1.5073x; 1.0148x over previous
//
#include <hip/hip_runtime.h>
#include <stdint.h>

#define Hs 96
#define Ws 96
#define HW 9216

typedef _Float16 h2 __attribute__((ext_vector_type(2)));
typedef _Float16 f16x8 __attribute__((ext_vector_type(8)));
typedef float f32x4 __attribute__((ext_vector_type(4)));

// nested-fma bilinear: 1 pk_mul + 3 pk_fma (FP contraction)
__device__ __forceinline__ unsigned interp4(h2 w00, h2 w01, h2 w10, h2 w11,
                                            unsigned a, unsigned bq, unsigned c,
                                            unsigned d) {
  h2 r = w10 * __builtin_bit_cast(h2, c) + w11 * __builtin_bit_cast(h2, d);
  r = w01 * __builtin_bit_cast(h2, bq) + r;
  r = w00 * __builtin_bit_cast(h2, a) + r;
  return __builtin_bit_cast(unsigned, r);
}

// ---- kernel 1: fused prep ----
// blk < 2304: NCHW fp32 -> NHWC fp16 transpose (32x-tile per block)
// blk >= 2304: weight fp32 [O][C][9] -> fp16 planes Wg[t*8+c8][o][8ch]
__global__ __launch_bounds__(256) void k_prep(const float* __restrict__ in,
                                              _Float16* __restrict__ cl,
                                              const float* __restrict__ w,
                                              _Float16* __restrict__ wg) {
  __shared__ _Float16 lt[32 * 68];
  int tid = threadIdx.x;
  int blk = blockIdx.x;
  if (blk >= 2304) {
    int i = (blk - 2304) * 256 + tid;        // 0..36863
    int o = i / 576;
    int r = i - o * 576;                     // tap*64 + c
    int t = r >> 6, c = r & 63;
    wg[((size_t)(t * 8 + (c >> 3)) * 64 + o) * 8 + (c & 7)] =
        (_Float16)w[(o * 64 + c) * 9 + t];
    return;
  }
  int xt = blk % 3;
  int rr = blk / 3;
  int y = rr % Hs;
  int b = rr / Hs;
  int x0 = xt * 32;
  {
    int xx = tid & 31, cc = tid >> 5;
    const float* src = in + (size_t)b * 64 * HW + y * Ws + x0 + xx;
#pragma unroll
    for (int i = 0; i < 8; ++i) {
      int c = cc * 8 + i;
      lt[xx * 68 + c] = (_Float16)src[(size_t)c * HW];
    }
  }
  __syncthreads();
  {
    int c4 = tid & 15, pg = tid >> 4;
    _Float16* dst = cl + ((size_t)(b * Hs + y) * Ws + x0) * 64 + c4 * 4;
#pragma unroll
    for (int i = 0; i < 2; ++i) {
      int x = pg * 2 + i;
      *(uint2*)(dst + (size_t)x * 64) = *(const uint2*)(lt + x * 68 + c4 * 4);
    }
  }
}

// ---- kernel 2: fused sampling + implicit GEMM, drain-free tap pipeline ----
// Block: 256 threads, 64 pixels. Grid: 1152 = 8 images (blk&7) x 144 tiles.
// All 1152 blocks resident at 5 blocks/CU -> zero tail.
// Sampling: 8-lane group <-> pixel, lane j <-> 16B channel chunk.
// GEMM: wave wv owns output channels [wv*16, wv*16+16).
__global__ __launch_bounds__(256, 5) void k_fused(
    const _Float16* __restrict__ incl, const float* __restrict__ off,
    const float* __restrict__ msk, const _Float16* __restrict__ wg,
    const float* __restrict__ bias, float* __restrict__ out) {
  __shared__ unsigned preA[576];     // 2,304 B
  __shared__ uint4 preW[576];        // 9,216 B (4 pre-duplicated h2 weights)
  __shared__ uint4 Vb[2][64 * 9];    // 18,432 B (9 uint4 = 144 B per pixel)

  int tid = threadIdx.x;
  int blk = blockIdx.x;
  int b = blk & 7;              // XCD swizzle: image b on XCD b
  int q0 = (blk >> 3) * 64;     // 144 pixel-tiles per image

  // phase pre: per-(pixel,tap) packed corner address + duplicated weights
  for (int i = tid; i < 576; i += 256) {
    int t = i >> 6, p = i & 63;
    int q = q0 + p;
    int qy = (int)(((unsigned)q * 43691u) >> 22);   // q/96 for q<9216
    int qx = q - qy * 96;
    int ty = t / 3, tx = t - ty * 3;
    float dy = off[(size_t)(b * 18 + 2 * t) * HW + q];
    float dx = off[(size_t)(b * 18 + 2 * t + 1) * HW + q];
    float mv = msk[(size_t)(b * 9 + t) * HW + q];
    float yf = (float)(qy - 1 + ty) + dy;
    float xf = (float)(qx - 1 + tx) + dx;
    float y0f = floorf(yf), x0f = floorf(xf);
    float wy = yf - y0f, wx = xf - x0f;
    int y0 = (int)y0f, x0i = (int)x0f;
    int y1 = y0 + 1, x1 = x0i + 1;
    bool yv0 = (y0 >= 0) && (y0 < Hs);
    bool yv1 = (y1 >= 0) && (y1 < Hs);
    bool xv0 = (x0i >= 0) && (x0i < Ws);
    bool xv1 = (x1 >= 0) && (x1 < Ws);
    int y0c = min(max(y0, 0), Hs - 1), y1c = min(max(y1, 0), Hs - 1);
    int x0c = min(max(x0i, 0), Ws - 1), x1c = min(max(x1, 0), Ws - 1);
    float omy = 1.f - wy, omx = 1.f - wx;
    float f00 = omy * omx * mv * ((yv0 && xv0) ? 1.f : 0.f);
    float f01 = omy * wx  * mv * ((yv0 && xv1) ? 1.f : 0.f);
    float f10 = wy  * omx * mv * ((yv1 && xv0) ? 1.f : 0.f);
    float f11 = wy  * wx  * mv * ((yv1 && xv1) ? 1.f : 0.f);
    preA[i] = ((unsigned)(b * HW + y0c * 96 + x0c) * 128u) |
              (unsigned)(x1c - x0c) | ((unsigned)(y1c - y0c) << 1);
    uint4 pw;
    pw.x = __builtin_bit_cast(unsigned, __builtin_amdgcn_cvt_pkrtz(f00, f00));
    pw.y = __builtin_bit_cast(unsigned, __builtin_amdgcn_cvt_pkrtz(f01, f01));
    pw.z = __builtin_bit_cast(unsigned, __builtin_amdgcn_cvt_pkrtz(f10, f10));
    pw.w = __builtin_bit_cast(unsigned, __builtin_amdgcn_cvt_pkrtz(f11, f11));
    preW[i] = pw;
  }
  __syncthreads();

  int j = tid & 7;
  int g = tid >> 3;            // 0..31 (sampling group)
  int lane = tid & 63, wv = tid >> 6;
  int n16 = lane & 15, q4 = lane >> 4;
  const char* inb = (const char*)incl;
  const uint4* Ag = (const uint4*)wg;   // plane p: Ag[p*64 + m]
  int arow = wv * 16 + n16;             // A-operand m index for this lane

  f32x4 acc[4];
#pragma unroll
  for (int pg = 0; pg < 4; ++pg) {
    f32x4 z = {0.f, 0.f, 0.f, 0.f};
    acc[pg] = z;
  }

  uint4 ga[2][4];     // gathers for current tap: 2 pixel-subgroups x 4 corners
  uint4 afn0, afn1;   // prefetched A-fragments (next tap)

#define ISSUE_GATHERS(T)                                                     \
  _Pragma("unroll") for (int it = 0; it < 2; ++it) {                         \
    int gg = g + it * 32;                                                    \
    unsigned ax = preA[(T) * 64 + gg];                                       \
    int a00 = (int)(ax & ~127u) + j * 16;                                    \
    int a01 = a00 + ((ax & 1) << 7);                                         \
    int a10 = a00 + ((ax & 2) * 6144);                                       \
    int a11 = a10 + ((ax & 1) << 7);                                         \
    ga[it][0] = *(const uint4*)(inb + a00);                                  \
    ga[it][1] = *(const uint4*)(inb + a01);                                  \
    ga[it][2] = *(const uint4*)(inb + a10);                                  \
    ga[it][3] = *(const uint4*)(inb + a11);                                  \
  }

  // prologue: tap 0 gathers + tap 0 A-fragments
  ISSUE_GATHERS(0)
  afn0 = Ag[(size_t)((0 + q4) * 64 + arow)];
  afn1 = Ag[(size_t)((4 + q4) * 64 + arow)];

#pragma unroll
  for (int t = 0; t < 9; ++t) {
    int buf = t & 1;
    // interp tap t (consumes ga; hw waits its vmcnt here)
    uint4 v0, v1;
#pragma unroll
    for (int it = 0; it < 2; ++it) {
      int gg = g + it * 32;
      uint4 pw = preW[t * 64 + gg];
      h2 w00 = __builtin_bit_cast(h2, pw.x);
      h2 w01 = __builtin_bit_cast(h2, pw.y);
      h2 w10 = __builtin_bit_cast(h2, pw.z);
      h2 w11 = __builtin_bit_cast(h2, pw.w);
      uint4 r;
      r.x = interp4(w00, w01, w10, w11, ga[it][0].x, ga[it][1].x, ga[it][2].x, ga[it][3].x);
      r.y = interp4(w00, w01, w10, w11, ga[it][0].y, ga[it][1].y, ga[it][2].y, ga[it][3].y);
      r.z = interp4(w00, w01, w10, w11, ga[it][0].z, ga[it][1].z, ga[it][2].z, ga[it][3].z);
      r.w = interp4(w00, w01, w10, w11, ga[it][0].w, ga[it][1].w, ga[it][2].w, ga[it][3].w);
      if (it == 0) v0 = r; else v1 = r;
    }
    uint4 afc0 = afn0, afc1 = afn1;
    Vb[buf][g * 9 + j] = v0;
    Vb[buf][(g + 32) * 9 + j] = v1;
    __syncthreads();   // vm queue ~empty here -> drain is cheap
    if (t < 8) {
      // issue next tap's loads; consumed before the NEXT barrier
      ISSUE_GATHERS(t + 1)
      afn0 = Ag[(size_t)(((t + 1) * 8 + q4) * 64 + arow)];
      afn1 = Ag[(size_t)(((t + 1) * 8 + 4 + q4) * 64 + arow)];
    }
    // MFMA on tap t: wave wv covers m in [wv*16, wv*16+16), all 64 pixels
#pragma unroll
    for (int pg = 0; pg < 4; ++pg) {
      f16x8 b0 = __builtin_bit_cast(f16x8, Vb[buf][(pg * 16 + n16) * 9 + q4]);
      f16x8 b1 = __builtin_bit_cast(f16x8, Vb[buf][(pg * 16 + n16) * 9 + 4 + q4]);
      acc[pg] = __builtin_amdgcn_mfma_f32_16x16x32_f16(
          __builtin_bit_cast(f16x8, afc0), b0, acc[pg], 0, 0, 0);
      acc[pg] = __builtin_amdgcn_mfma_f32_16x16x32_f16(
          __builtin_bit_cast(f16x8, afc1), b1, acc[pg], 0, 0, 0);
    }
  }
#undef ISSUE_GATHERS

  // epilogue: D col = pixel (n16), row m = wv*16 + q4*4 + r
  int m0 = wv * 16 + q4 * 4;
  float bv[4];
#pragma unroll
  for (int r = 0; r < 4; ++r) bv[r] = bias[m0 + r];
#pragma unroll
  for (int pg = 0; pg < 4; ++pg) {
    int col = q0 + pg * 16 + n16;
    float* op = out + (size_t)b * 64 * HW + col;
#pragma unroll
    for (int r = 0; r < 4; ++r)
      op[(size_t)(m0 + r) * HW] = acc[pg][r] + bv[r];
  }
}

extern "C" void kernel_launch(void* const* d_in, const int* in_sizes, int n_in,
                              void* d_out, int out_size, void* d_ws, size_t ws_size,
                              hipStream_t stream) {
  const float* input = (const float*)d_in[0];
  const float* offset = (const float*)d_in[1];
  const float* mask = (const float*)d_in[2];
  const float* weight = (const float*)d_in[3];
  const float* bias = (const float*)d_in[4];
  float* out = (float*)d_out;

  _Float16* incl = (_Float16*)d_ws;                              // 9,437,184 B
  _Float16* wg = (_Float16*)((char*)d_ws + 9437184);             // 73,728 B

  k_prep<<<dim3(2448), dim3(256), 0, stream>>>(input, incl, weight, wg);
  k_fused<<<dim3(1152), dim3(256), 0, stream>>>(incl, offset, mask, wg, bias, out);
}